// Round 10
// baseline (66.053 us; speedup 1.0000x reference)
//
#include <hip/hip_runtime.h>
#include <stdint.h>

typedef __bf16 bf16_t;
typedef __bf16 bf16x8 __attribute__((ext_vector_type(8)));
typedef float f32x4 __attribute__((ext_vector_type(4)));

#define M_DIM 16384
#define N_DIM 1024
#define K_DIM 1024
#define BM 256
#define BN 128
#define BK 32
#define NT (K_DIM / BK)     // 32 K-tiles
#define A_SLOT 16384        // bytes: 256 rows x 64B (bf16), R8-proven geometry

// ------- W: binarize (exact reference semantics) + transpose to [N][K] -------
__global__ void bin_transpose_w(const float* __restrict__ W,
                                unsigned short* __restrict__ WbT) {
    __shared__ unsigned short t[64][68];
    int tj = blockIdx.x;                   // n tile
    int ti = blockIdx.y;                   // k tile
    int tid = threadIdx.x;
    int c4 = (tid & 15) * 4;
    int r0 = tid >> 4;
#pragma unroll
    for (int p = 0; p < 4; ++p) {
        int r = r0 + p * 16;
        float4 v = *(const float4*)(W + (size_t)(ti * 64 + r) * N_DIM + tj * 64 + c4);
        // reference: +1 iff (w+1)/2 > 0.5 (round-half-even at exactly 0.5 -> -1)
        t[r][c4 + 0] = ((v.x + 1.0f) * 0.5f > 0.5f) ? 0x3F80 : 0xBF80;
        t[r][c4 + 1] = ((v.y + 1.0f) * 0.5f > 0.5f) ? 0x3F80 : 0xBF80;
        t[r][c4 + 2] = ((v.z + 1.0f) * 0.5f > 0.5f) ? 0x3F80 : 0xBF80;
        t[r][c4 + 3] = ((v.w + 1.0f) * 0.5f > 0.5f) ? 0x3F80 : 0xBF80;
    }
    __syncthreads();
#pragma unroll
    for (int p = 0; p < 4; ++p) {
        int rn = r0 + p * 16;
        ushort4 o;
        o.x = t[c4 + 0][rn];
        o.y = t[c4 + 1][rn];
        o.z = t[c4 + 2][rn];
        o.w = t[c4 + 3][rn];
        *(ushort4*)(WbT + (size_t)(tj * 64 + rn) * K_DIM + ti * 64 + c4) = o;
    }
}

// ------- fused GEMM: A reg-cvt->LDS (bf16), B direct L2->reg, 4 waves -------
__global__ __launch_bounds__(256, 2) void bgemm(const float* __restrict__ X,
                                                const bf16_t* __restrict__ Bt,
                                                const float* __restrict__ bias,
                                                float* __restrict__ C) {
    __shared__ __align__(16) char lds[2 * A_SLOT];   // 32 KB, A only

    const int nwg = (M_DIM / BM) * (N_DIM / BN);   // 512, %8==0
    int bid = blockIdx.x;
    int swz = (bid & 7) * (nwg >> 3) + (bid >> 3); // XCD-aware, bijective
    int tile_m = swz >> 3;
    int tile_n = swz & 7;                          // consecutive swz share A panel
    int bm0 = tile_m * BM;
    int bn0 = tile_n * BN;

    int tid = threadIdx.x;
    int w = tid >> 6, l = tid & 63;    // 4 waves: 2(M) x 2(N)
    int wr = w >> 1, wc = w & 1;       // per-wave 128x64 output
    int lr = l & 15, lk = l >> 4;

    // A staging assignment: thread covers rows (tid>>2)+64p (p=0..3), chunk ac
    int ar = tid >> 2, ac = tid & 3;
    // B-direct per-lane base: row = bn0 + wc*64 + lr (+n*16), k-chunk lk
    const bf16_t* bbase = Bt + (size_t)(bn0 + wc * 64 + lr) * K_DIM + lk * 8;

    f32x4 acc[8][4];
#pragma unroll
    for (int m = 0; m < 8; ++m)
#pragma unroll
        for (int n = 0; n < 4; ++n)
            acc[m][n] = (f32x4)(0.0f);

    float4 a_st[4][2];                 // staged A f32 (32 VGPR)
    bf16x8 b_act[4], b_st[4];          // B frags: active / staged

    auto loadA = [&](int t) {
#pragma unroll
        for (int p = 0; p < 4; ++p) {
            const float4* s = (const float4*)(X + (size_t)(bm0 + ar + 64 * p) * K_DIM
                                              + t * BK + ac * 8);
            a_st[p][0] = s[0];
            a_st[p][1] = s[1];
        }
    };
    auto loadB = [&](int t, bf16x8* d) {
#pragma unroll
        for (int n = 0; n < 4; ++n)
            d[n] = *(const bf16x8*)(bbase + (size_t)n * 16 * K_DIM + t * BK);
    };
    auto writeA = [&](int t) {         // cvt f32->bf16 (RNE via cast) + swizzled write
#pragma unroll
        for (int p = 0; p < 4; ++p) {
            bf16x8 v;
            v[0] = (__bf16)a_st[p][0].x; v[1] = (__bf16)a_st[p][0].y;
            v[2] = (__bf16)a_st[p][0].z; v[3] = (__bf16)a_st[p][0].w;
            v[4] = (__bf16)a_st[p][1].x; v[5] = (__bf16)a_st[p][1].y;
            v[6] = (__bf16)a_st[p][1].z; v[7] = (__bf16)a_st[p][1].w;
            int r = ar + 64 * p;
            *(bf16x8*)(lds + (t & 1) * A_SLOT + r * 64
                       + ((ac ^ ((r >> 1) & 3)) * 16)) = v;
        }
    };

    // ---- prologue: tile 0 staged + written; tile 1 loads in flight ----
    loadA(0);
    loadB(0, b_act);
    writeA(0);
    loadA(1);
    loadB(1, b_st);
    asm volatile("s_waitcnt lgkmcnt(0)" ::: "memory");
    __builtin_amdgcn_sched_barrier(0);
    __builtin_amdgcn_s_barrier();

    for (int t = 0; t < NT; ++t) {
        const char* Ab = lds + (t & 1) * A_SLOT;

        // ---- compute: 8 ds_read_b128 + 32 MFMA; B frags from registers ----
#pragma unroll
        for (int m = 0; m < 8; ++m) {
            int r = wr * 128 + m * 16 + lr;
            bf16x8 afr = *(const bf16x8*)(Ab + r * 64 + ((lk ^ ((r >> 1) & 3)) * 16));
#pragma unroll
            for (int n = 0; n < 4; ++n)
                acc[m][n] = __builtin_amdgcn_mfma_f32_16x16x32_bf16(
                    afr, b_act[n], acc[m][n], 0, 0, 0);
        }

        // ---- post: write A(t+1) (loads covered by compute), rotate B, prefetch t+2
        if (t + 1 < NT) {
            writeA(t + 1);
#pragma unroll
            for (int n = 0; n < 4; ++n) b_act[n] = b_st[n];
            if (t + 2 < NT) {
                loadA(t + 2);
                loadB(t + 2, b_st);
            }
            asm volatile("s_waitcnt lgkmcnt(0)" ::: "memory");
            __builtin_amdgcn_sched_barrier(0);
            __builtin_amdgcn_s_barrier();
        }
    }

    // ---- epilogue: C/D layout col = lane&15, row = (lane>>4)*4 + reg ----
#pragma unroll
    for (int n = 0; n < 4; ++n) {
        int col = bn0 + wc * 64 + n * 16 + lr;
        float bv = bias[col];
#pragma unroll
        for (int m = 0; m < 8; ++m) {
            int row0 = bm0 + wr * 128 + m * 16 + lk * 4;
#pragma unroll
            for (int j = 0; j < 4; ++j)
                C[(size_t)(row0 + j) * N_DIM + col] = acc[m][n][j] + bv;
        }
    }
}

// ---------------- fallback (only if workspace too small) ----------------
__global__ void naive_bin_dense(const float* __restrict__ x,
                                const float* __restrict__ W,
                                const float* __restrict__ b,
                                float* __restrict__ out) {
    int col = blockIdx.x * 256 + threadIdx.x;
    int row = blockIdx.y;
    float acc = 0.0f;
    for (int k = 0; k < K_DIM; ++k) {
        float s = ((W[(size_t)k * N_DIM + col] + 1.0f) * 0.5f > 0.5f) ? 1.0f : -1.0f;
        acc += x[(size_t)row * K_DIM + k] * s;
    }
    out[(size_t)row * N_DIM + col] = acc + b[col];
}

extern "C" void kernel_launch(void* const* d_in, const int* in_sizes, int n_in,
                              void* d_out, int out_size, void* d_ws, size_t ws_size,
                              hipStream_t stream) {
    const float* x = (const float*)d_in[0];
    const float* W = (const float*)d_in[1];
    const float* b = (const float*)d_in[2];
    float* out = (float*)d_out;

    size_t wb_bytes = (size_t)K_DIM * N_DIM * sizeof(unsigned short);

    if (ws_size >= wb_bytes) {
        unsigned short* wbt = (unsigned short*)d_ws;
        hipLaunchKernelGGL(bin_transpose_w, dim3(N_DIM / 64, K_DIM / 64), dim3(256),
                           0, stream, W, wbt);
        hipLaunchKernelGGL(bgemm, dim3((M_DIM / BM) * (N_DIM / BN)), dim3(256), 0, stream,
                           x, (const bf16_t*)wbt, b, out);
    } else {
        hipLaunchKernelGGL(naive_bin_dense, dim3(N_DIM / 256, M_DIM), dim3(256),
                           0, stream, x, W, b, out);
    }
}

// Round 11
// 55.255 us; speedup vs baseline: 1.1954x; 1.1954x over previous
//
#include <hip/hip_runtime.h>
#include <stdint.h>

typedef __bf16 bf16_t;
typedef __bf16 bf16x8 __attribute__((ext_vector_type(8)));
typedef float f32x4 __attribute__((ext_vector_type(4)));

#define M_DIM 16384
#define N_DIM 1024
#define K_DIM 1024
#define BM 128
#define BN 256
#define BK 32
#define NT (K_DIM / BK)          // 32 K-tiles
#define A_SLOT 16384             // bytes: 2 planes x (128 rows x 64B f32)
#define B_SLOT 16384             // bytes: 256 rows x 64B (bf16)
#define B_BASE 32768             // byte offset of B region
// LDS: A[2] + B[2] = 64 KB -> 2 blocks/CU

// ------- W: binarize (exact reference semantics) + transpose to [N][K] -------
__global__ void bin_transpose_w(const float* __restrict__ W,
                                unsigned short* __restrict__ WbT) {
    __shared__ unsigned short t[64][68];
    int tj = blockIdx.x;                   // n tile
    int ti = blockIdx.y;                   // k tile
    int tid = threadIdx.x;
    int c4 = (tid & 15) * 4;
    int r0 = tid >> 4;
#pragma unroll
    for (int p = 0; p < 4; ++p) {
        int r = r0 + p * 16;
        float4 v = *(const float4*)(W + (size_t)(ti * 64 + r) * N_DIM + tj * 64 + c4);
        // reference: +1 iff (w+1)/2 > 0.5 (round-half-even at exactly 0.5 -> -1)
        t[r][c4 + 0] = ((v.x + 1.0f) * 0.5f > 0.5f) ? 0x3F80 : 0xBF80;
        t[r][c4 + 1] = ((v.y + 1.0f) * 0.5f > 0.5f) ? 0x3F80 : 0xBF80;
        t[r][c4 + 2] = ((v.z + 1.0f) * 0.5f > 0.5f) ? 0x3F80 : 0xBF80;
        t[r][c4 + 3] = ((v.w + 1.0f) * 0.5f > 0.5f) ? 0x3F80 : 0xBF80;
    }
    __syncthreads();
#pragma unroll
    for (int p = 0; p < 4; ++p) {
        int rn = r0 + p * 16;
        ushort4 o;
        o.x = t[c4 + 0][rn];
        o.y = t[c4 + 1][rn];
        o.z = t[c4 + 2][rn];
        o.w = t[c4 + 3][rn];
        *(ushort4*)(WbT + (size_t)(tj * 64 + rn) * K_DIM + ti * 64 + c4) = o;
    }
}

// ------- fused cvt-on-read GEMM: C = cvt_bf16(X) * Bt^T + bias -------
__device__ __forceinline__ void gload16(const void* g, const void* l) {
    __builtin_amdgcn_global_load_lds(
        (const __attribute__((address_space(1))) void*)(g),
        (__attribute__((address_space(3))) void*)(l),
        16, 0, 0);
}

__global__ __launch_bounds__(512, 4) void bgemm(const float* __restrict__ X,
                                                const bf16_t* __restrict__ Bt,
                                                const float* __restrict__ bias,
                                                float* __restrict__ C) {
    __shared__ __align__(16) char lds[2 * A_SLOT + 2 * B_SLOT];   // 64 KB

    const int nwg = (M_DIM / BM) * (N_DIM / BN);   // 512, %8==0
    int bid = blockIdx.x;
    int swz = (bid & 7) * (nwg >> 3) + (bid >> 3); // XCD-aware, bijective
    int tile_n = swz & 3;                          // consecutive swz share A panel
    int tile_m = swz >> 2;
    int bm0 = tile_m * BM;
    int bn0 = tile_n * BN;

    int tid = threadIdx.x;
    int w = tid >> 6, l = tid & 63;    // 8 waves: 2(M) x 4(N)
    int wr = w >> 2, wc = w & 3;       // per-wave 64x64 output
    int lr = l & 15, lk = l >> 4;

    // ---- staging (gload_lds, linear LDS dest, pre-swizzled per-lane source) ----
    // A (f32): [2 planes][128 rows][64B]; within plane: slot = chunk ^ ((r>>1)&3)
    //   (R8-measured-zero bank geometry: 64B rows + 2-bit row XOR)
    int arow = tid >> 2;                       // 0..127 per call
    int achk = (tid & 3) ^ ((tid >> 3) & 3);   // logical 16B chunk at this slot
    auto stageA = [&](int t, int p) {          // p = K-half plane (8 KB per call)
        gload16(X + (size_t)(bm0 + arow) * K_DIM + t * BK + p * 16 + achk * 4,
                lds + (t & 1) * A_SLOT + p * 8192 + tid * 16);
    };
    // B (bf16): rows 64B; slot = chunk ^ ((r>>1)&3)  (same proven geometry)
    int brow = tid >> 2;                       // 0..127 per call (+c*128)
    int bchk = (tid & 3) ^ ((brow >> 1) & 3);
    auto stageB = [&](int t, int c) {
        gload16(Bt + (size_t)(bn0 + c * 128 + brow) * K_DIM + t * BK + bchk * 8,
                lds + B_BASE + (t & 1) * B_SLOT + c * 8192 + tid * 16);
    };

    f32x4 acc[4][4];
#pragma unroll
    for (int m = 0; m < 4; ++m)
#pragma unroll
        for (int n = 0; n < 4; ++n)
            acc[m][n] = (f32x4)(0.0f);

    // ---- prologue: stage tile 0, drain, barrier ----
    stageA(0, 0); stageA(0, 1); stageB(0, 0); stageB(0, 1);
    asm volatile("s_waitcnt vmcnt(0)" ::: "memory");
    __builtin_amdgcn_s_barrier();

    for (int t = 0; t < NT; ++t) {
        // ---- stage tile t+1 early (opposite slot; last read at t-1, retired) ----
        if (t + 1 < NT) {
            stageA(t + 1, 0); stageA(t + 1, 1);
            stageB(t + 1, 0); stageB(t + 1, 1);
        }

        const char* Ab = lds + (t & 1) * A_SLOT;
        const char* Bb = lds + B_BASE + (t & 1) * B_SLOT;

        // ---- B frags: bf16 direct (swizzled read, proven conflict-free) ----
        bf16x8 bfr[4];
#pragma unroll
        for (int n = 0; n < 4; ++n) {
            int br = wc * 64 + n * 16 + lr;
            bfr[n] = *(const bf16x8*)(Bb + br * 64 + ((lk ^ ((br >> 1) & 3)) * 16));
        }
        // ---- A frags: plane = lk>>1, two 16B f32 reads + in-reg RNE cvt ----
#pragma unroll
        for (int m = 0; m < 4; ++m) {
            int r = wr * 64 + m * 16 + lr;
            const char* pb = Ab + (lk >> 1) * 8192 + r * 64;
            int slot_lo = (2 * (lk & 1)) ^ ((r >> 1) & 3);
            float4 lo = *(const float4*)(pb + slot_lo * 16);
            float4 hi = *(const float4*)(pb + (slot_lo ^ 1) * 16);
            bf16x8 afr;
            afr[0] = (__bf16)lo.x; afr[1] = (__bf16)lo.y;
            afr[2] = (__bf16)lo.z; afr[3] = (__bf16)lo.w;
            afr[4] = (__bf16)hi.x; afr[5] = (__bf16)hi.y;
            afr[6] = (__bf16)hi.z; afr[7] = (__bf16)hi.w;
#pragma unroll
            for (int n = 0; n < 4; ++n)
                acc[m][n] = __builtin_amdgcn_mfma_f32_16x16x32_bf16(
                    afr, bfr[n], acc[m][n], 0, 0, 0);
        }

        // ---- boundary: drain staging of t+1, rendezvous ----
        if (t + 1 < NT) {
            asm volatile("s_waitcnt vmcnt(0)" ::: "memory");
            __builtin_amdgcn_s_barrier();
        }
    }

    // ---- epilogue: C/D layout col = lane&15, row = (lane>>4)*4 + reg ----
#pragma unroll
    for (int n = 0; n < 4; ++n) {
        int col = bn0 + wc * 64 + n * 16 + lr;
        float bv = bias[col];
#pragma unroll
        for (int m = 0; m < 4; ++m) {
            int row0 = bm0 + wr * 64 + m * 16 + lk * 4;
#pragma unroll
            for (int j = 0; j < 4; ++j)
                C[(size_t)(row0 + j) * N_DIM + col] = acc[m][n][j] + bv;
        }
    }
}

// ---------------- fallback (only if workspace too small) ----------------
__global__ void naive_bin_dense(const float* __restrict__ x,
                                const float* __restrict__ W,
                                const float* __restrict__ b,
                                float* __restrict__ out) {
    int col = blockIdx.x * 256 + threadIdx.x;
    int row = blockIdx.y;
    float acc = 0.0f;
    for (int k = 0; k < K_DIM; ++k) {
        float s = ((W[(size_t)k * N_DIM + col] + 1.0f) * 0.5f > 0.5f) ? 1.0f : -1.0f;
        acc += x[(size_t)row * K_DIM + k] * s;
    }
    out[(size_t)row * N_DIM + col] = acc + b[col];
}

extern "C" void kernel_launch(void* const* d_in, const int* in_sizes, int n_in,
                              void* d_out, int out_size, void* d_ws, size_t ws_size,
                              hipStream_t stream) {
    const float* x = (const float*)d_in[0];
    const float* W = (const float*)d_in[1];
    const float* b = (const float*)d_in[2];
    float* out = (float*)d_out;

    size_t wb_bytes = (size_t)K_DIM * N_DIM * sizeof(unsigned short);

    if (ws_size >= wb_bytes) {
        unsigned short* wbt = (unsigned short*)d_ws;
        hipLaunchKernelGGL(bin_transpose_w, dim3(N_DIM / 64, K_DIM / 64), dim3(256),
                           0, stream, W, wbt);
        hipLaunchKernelGGL(bgemm, dim3((M_DIM / BM) * (N_DIM / BN)), dim3(512), 0, stream,
                           x, (const bf16_t*)wbt, b, out);
    } else {
        hipLaunchKernelGGL(naive_bin_dense, dim3(N_DIM / 256, M_DIM), dim3(256),
                           0, stream, x, W, b, out);
    }
}